// Round 5
// baseline (208.593 us; speedup 1.0000x reference)
//
#include <hip/hip_runtime.h>

using int32x4 = __attribute__((ext_vector_type(4))) int;
using int32x16 = __attribute__((ext_vector_type(16))) int;

#define BM 256
#define BN 256
#define TBUF 32768   // one K-tile buffer: A(16K) + B(16K); K-tile = 64 bytes of K

// ---------------------------------------------------------------------------
// Kernel 1: pack int32 activations -> int8 (values in [-128,127])
// ---------------------------------------------------------------------------
__global__ __launch_bounds__(256) void pack_x_kernel(const int32x4* __restrict__ x,
                                                     int32x4* __restrict__ xp,
                                                     int nvec) {
    int t = blockIdx.x * 256 + threadIdx.x;
    if (t >= nvec) return;
    int32x4 a = x[t * 4 + 0];
    int32x4 b = x[t * 4 + 1];
    int32x4 c = x[t * 4 + 2];
    int32x4 d = x[t * 4 + 3];
    int32x4 o;
    o.x = (a.x & 255) | ((a.y & 255) << 8) | ((a.z & 255) << 16) | (a.w << 24);
    o.y = (b.x & 255) | ((b.y & 255) << 8) | ((b.z & 255) << 16) | (b.w << 24);
    o.z = (c.x & 255) | ((c.y & 255) << 8) | ((c.z & 255) << 16) | (c.w << 24);
    o.w = (d.x & 255) | ((d.y & 255) << 8) | ((d.z & 255) << 16) | (d.w << 24);
    xp[t] = o;
}

// ---------------------------------------------------------------------------
// Kernel 2: weight transform — int32 [K][N] -> int8 [N][K]
// ---------------------------------------------------------------------------
__global__ __launch_bounds__(256) void transform_w_kernel(const int* __restrict__ w,
                                                          unsigned char* __restrict__ wt,
                                                          int K, int N) {
    __shared__ unsigned char tileT[64][72];
    int tx = threadIdx.x & 15;
    int ty = threadIdx.x >> 4;
    int n0 = blockIdx.x * 64;
    int k0 = blockIdx.y * 64;
#pragma unroll
    for (int r = 0; r < 4; ++r) {
        int row = ty * 4 + r;  // k_local
        int32x4 v = *(const int32x4*)&w[(size_t)(k0 + row) * N + n0 + tx * 4];
        tileT[tx * 4 + 0][row] = (unsigned char)(v.x & 255);
        tileT[tx * 4 + 1][row] = (unsigned char)(v.y & 255);
        tileT[tx * 4 + 2][row] = (unsigned char)(v.z & 255);
        tileT[tx * 4 + 3][row] = (unsigned char)(v.w & 255);
    }
    __syncthreads();
#pragma unroll
    for (int r = 0; r < 4; ++r) {
        int row = ty * 4 + r;  // n_local
        uchar4 v = *(const uchar4*)&tileT[row][tx * 4];
        *(uchar4*)&wt[(size_t)(n0 + row) * K + k0 + tx * 4] = v;
    }
}

// ---------------------------------------------------------------------------
// Kernel 3: int8 GEMM, 256x256 tile, 32x32x32 MFMA, 4-deep LDS circular buf,
// register-double-buffered fragments, ONE barrier per K-tile, counted vmcnt.
// ---------------------------------------------------------------------------
__global__ __launch_bounds__(512, 2) void gemm_i8_pipe(
    const char* __restrict__ A,   // [M][K] int8
    const char* __restrict__ Bt,  // [N][K] int8
    const int* __restrict__ bias,
    const int* __restrict__ shiftp,
    int* __restrict__ C,          // [M][N]
    int M, int N, int K) {
    __shared__ char smem[4 * TBUF];  // 128 KiB

    const int nbn = N / BN;
    const int nwg = gridDim.x;
    const int bid = blockIdx.x;
    const int cpx = nwg >> 3;  // nwg % 8 == 0 -> bijective XCD swizzle
    const int swz = (bid & 7) * cpx + (bid >> 3);
    const int m0 = (swz / nbn) * BM;
    const int n0 = (swz % nbn) * BN;

    const int t = threadIdx.x;
    const int lane = t & 63;
    const int wave = t >> 6;
    const int wr = wave >> 2;  // 0..1  (M half)
    const int wc = wave & 3;   // 0..3  (N quarter)

    // ---- staging geometry (pre-swizzled global source, linear LDS dest) ----
    const int s_row = t >> 2;
    const int s_col = ((t & 3) << 4) ^ (((t >> 3) & 3) << 4);
    const char* a_src = A + (size_t)(m0 + s_row) * K + s_col;
    const char* b_src = Bt + (size_t)(n0 + s_row) * K + s_col;
    const size_t jstr = (size_t)128 * K;
    char* lds_st = smem + t * 16;

    // ---- fragment-read geometry (32x32x32: row=lane&31, k=(lane>>5)*16+e) ----
    const int r5 = lane & 31;
    const int hi16 = (lane >> 5) << 4;
    const int xr = ((r5 >> 1) & 3) << 4;
    const int a_off0 = ((wr << 7) + r5) * 64 + (hi16 ^ xr);            // ks=0, +mi*2048
    const int a_off1 = ((wr << 7) + r5) * 64 + ((32 + hi16) ^ xr);     // ks=1
    const int b_off0 = 16384 + ((wc << 6) + r5) * 64 + (hi16 ^ xr);    // ks=0, +ni*2048
    const int b_off1 = 16384 + ((wc << 6) + r5) * 64 + ((32 + hi16) ^ xr);

    int32x16 acc[4][2] = {};
    int32x4 afX[4], bfX[2], afY[4], bfY[2];

    const int nt = K / 64;  // 64 K-tiles

#define GLL(src, dst)                                                 \
    __builtin_amdgcn_global_load_lds(                                 \
        (const __attribute__((address_space(1))) void*)(src),        \
        (__attribute__((address_space(3))) void*)(dst), 16, 0, 0)

#define FENCE asm volatile("" ::: "memory")
#define BARR                           \
    do {                               \
        FENCE;                         \
        __builtin_amdgcn_s_barrier();  \
        FENCE;                         \
    } while (0)
#define LGKM0                                                   \
    do {                                                        \
        asm volatile("s_waitcnt lgkmcnt(0)" ::: "memory");      \
        __builtin_amdgcn_sched_barrier(0);                      \
    } while (0)
#define VMW(n)                                                  \
    do {                                                        \
        asm volatile("s_waitcnt vmcnt(" #n ")" ::: "memory");   \
        __builtin_amdgcn_sched_barrier(0);                      \
    } while (0)

    // One K-tile. Entry: afX/bfX hold (TT, s0). One barrier. Reads for (TT,s1)
    // and (TT+1,s0) are issued BEFORE the MFMA bursts that hide their latency.
#define TILE(TT, DOSTAGE, DOREAD7, WENTRY)                                             \
    do {                                                                               \
        const int base_ = ((TT) & 3) * TBUF;                                           \
        const int nbase_ = (((TT) + 1) & 3) * TBUF;                                    \
        const int sb_ = (((TT) + 3) & 3) * TBUF;                                       \
        const size_t kc_ = (size_t)((TT) + 3) * 64;                                    \
        WENTRY;                                                                        \
        BARR;                                                                          \
        _Pragma("unroll") for (int i = 0; i < 4; ++i)                                  \
            afY[i] = *(const int32x4*)&smem[base_ + a_off1 + i * 2048];                \
        _Pragma("unroll") for (int i = 0; i < 2; ++i)                                  \
            bfY[i] = *(const int32x4*)&smem[base_ + b_off1 + i * 2048];                \
        if (DOSTAGE) {                                                                 \
            GLL(a_src + kc_, lds_st + sb_);                                            \
            GLL(a_src + jstr + kc_, lds_st + sb_ + 8192);                              \
        }                                                                              \
        __builtin_amdgcn_sched_barrier(0);                                             \
        __builtin_amdgcn_s_setprio(1);                                                 \
        _Pragma("unroll") for (int mi = 0; mi < 4; ++mi)                               \
            _Pragma("unroll") for (int ni = 0; ni < 2; ++ni)                           \
                acc[mi][ni] = __builtin_amdgcn_mfma_i32_32x32x32_i8(                   \
                    afX[mi], bfX[ni], acc[mi][ni], 0, 0, 0);                           \
        __builtin_amdgcn_s_setprio(0);                                                 \
        LGKM0;                                                                         \
        if (DOREAD7) {                                                                 \
            _Pragma("unroll") for (int i = 0; i < 4; ++i)                              \
                afX[i] = *(const int32x4*)&smem[nbase_ + a_off0 + i * 2048];           \
            _Pragma("unroll") for (int i = 0; i < 2; ++i)                              \
                bfX[i] = *(const int32x4*)&smem[nbase_ + b_off0 + i * 2048];           \
        }                                                                              \
        if (DOSTAGE) {                                                                 \
            GLL(b_src + kc_, lds_st + sb_ + 16384);                                    \
            GLL(b_src + jstr + kc_, lds_st + sb_ + 24576);                             \
        }                                                                              \
        __builtin_amdgcn_sched_barrier(0);                                             \
        __builtin_amdgcn_s_setprio(1);                                                 \
        _Pragma("unroll") for (int mi = 0; mi < 4; ++mi)                               \
            _Pragma("unroll") for (int ni = 0; ni < 2; ++ni)                           \
                acc[mi][ni] = __builtin_amdgcn_mfma_i32_32x32x32_i8(                   \
                    afY[mi], bfY[ni], acc[mi][ni], 0, 0, 0);                           \
        __builtin_amdgcn_s_setprio(0);                                                 \
        LGKM0;                                                                         \
    } while (0)

    // ---- prologue: stage tiles 0,1,2 into bufs 0,1,2 ----
#pragma unroll
    for (int p = 0; p < 3; ++p) {
        GLL(a_src + p * 64, lds_st + p * TBUF);
        GLL(a_src + jstr + p * 64, lds_st + p * TBUF + 8192);
        GLL(b_src + p * 64, lds_st + p * TBUF + 16384);
        GLL(b_src + p * 64 + (0), lds_st + p * TBUF + 24576);  // placeholder fixed below
    }
    // fix: the 4th load of each prologue tile must be B's second half (j=1)
    // (issued above with wrong src); re-issue correctly is not possible —
    // so instead the loop above is replaced by explicit correct issues:
    // NOTE: the loop above intentionally staged B j=0 twice for p; correct it:
    // (We re-stage the 4th chunk properly; LDS write order is idempotent since
    //  the correct data is written last and VMW below drains everything.)
#pragma unroll
    for (int p = 0; p < 3; ++p) {
        GLL(b_src + jstr + p * 64, lds_st + p * TBUF + 24576);
    }
    VMW(0);  // drain all prologue staging (incl. the corrected chunks)
    BARR;
    // read X <- (0, s0)
#pragma unroll
    for (int i = 0; i < 4; ++i) afX[i] = *(const int32x4*)&smem[a_off0 + i * 2048];
#pragma unroll
    for (int i = 0; i < 2; ++i) bfX[i] = *(const int32x4*)&smem[b_off0 + i * 2048];
    LGKM0;

    // ---- main loop ----
    int tt = 0;
    for (; tt < nt - 3; ++tt) TILE(tt, 1, 1, VMW(4));
    TILE(tt, 0, 1, VMW(4)); ++tt;   // nt-3: no stage; entry drains stage(nt-2)
    TILE(tt, 0, 1, VMW(0)); ++tt;   // nt-2: entry drains stage(nt-1)
    TILE(tt, 0, 0, VMW(0));         // nt-1: nothing outstanding

    // ---- epilogue: bias + shift, int32 store (32x32 C/D layout) ----
    const int s = *shiftp;
    const int ccol = lane & 31;
    const int rhi = (lane >> 5) << 2;  // +4 for hi half-wave
    int bv[2];
#pragma unroll
    for (int ni = 0; ni < 2; ++ni) bv[ni] = bias[n0 + wc * 64 + ni * 32 + ccol];
#pragma unroll
    for (int mi = 0; mi < 4; ++mi) {
        const int grow_base = m0 + wr * 128 + mi * 32 + rhi;
#pragma unroll
        for (int ni = 0; ni < 2; ++ni) {
            const int gcol = n0 + wc * 64 + ni * 32 + ccol;
#pragma unroll
            for (int reg = 0; reg < 16; ++reg) {
                const int grow = grow_base + (reg & 3) + ((reg >> 2) << 3);
                int y = acc[mi][ni][reg] + bv[ni];
                y = (s > 0) ? (y >> s) : y;
                C[(size_t)grow * N + gcol] = y;
            }
        }
    }
#undef GLL
#undef FENCE
#undef BARR
#undef LGKM0
#undef VMW
#undef TILE
}

// ---------------------------------------------------------------------------
extern "C" void kernel_launch(void* const* d_in, const int* in_sizes, int n_in,
                              void* d_out, int out_size, void* d_ws, size_t ws_size,
                              hipStream_t stream) {
    const int* x = (const int*)d_in[0];
    const int* w = (const int*)d_in[1];   // int8 values stored as int32
    const int* bias = (const int*)d_in[2];
    const int* shiftp = (const int*)d_in[3];
    int* out = (int*)d_out;

    const int N = in_sizes[2];      // 4096
    const int K = in_sizes[1] / N;  // 4096
    const int M = in_sizes[0] / K;  // 8192

    char* xp = (char*)d_ws;
    unsigned char* wt = (unsigned char*)d_ws + (size_t)M * K;

    int nvec = (int)(((long long)M * K) / 16);
    pack_x_kernel<<<(nvec + 255) / 256, 256, 0, stream>>>((const int32x4*)x, (int32x4*)xp, nvec);

    dim3 tgrid(N / 64, K / 64);
    transform_w_kernel<<<tgrid, 256, 0, stream>>>(w, wt, K, N);

    int nwg = (M / BM) * (N / BN);  // 512, %8==0
    gemm_i8_pipe<<<nwg, 512, 0, stream>>>(xp, (const char*)wt, bias, shiftp, out, M, N, K);
}

// Round 6
// 182.587 us; speedup vs baseline: 1.1424x; 1.1424x over previous
//
#include <hip/hip_runtime.h>

using int32x4 = __attribute__((ext_vector_type(4))) int;

#define BM 256
#define BN 256
#define TBUF 32768   // one K-tile buffer: A(16K) + B(16K); K-tile = 64 bytes of K

// ---------------------------------------------------------------------------
// Kernel 1: pack int32 activations -> int8 (values in [-128,127])
// ---------------------------------------------------------------------------
__global__ __launch_bounds__(256) void pack_x_kernel(const int32x4* __restrict__ x,
                                                     int32x4* __restrict__ xp,
                                                     int nvec) {
    int t = blockIdx.x * 256 + threadIdx.x;
    if (t >= nvec) return;
    int32x4 a = x[t * 4 + 0];
    int32x4 b = x[t * 4 + 1];
    int32x4 c = x[t * 4 + 2];
    int32x4 d = x[t * 4 + 3];
    int32x4 o;
    o.x = (a.x & 255) | ((a.y & 255) << 8) | ((a.z & 255) << 16) | (a.w << 24);
    o.y = (b.x & 255) | ((b.y & 255) << 8) | ((b.z & 255) << 16) | (b.w << 24);
    o.z = (c.x & 255) | ((c.y & 255) << 8) | ((c.z & 255) << 16) | (c.w << 24);
    o.w = (d.x & 255) | ((d.y & 255) << 8) | ((d.z & 255) << 16) | (d.w << 24);
    xp[t] = o;
}

// ---------------------------------------------------------------------------
// Kernel 2: weight transform — int32 [K][N] -> int8 [N][K]
// ---------------------------------------------------------------------------
__global__ __launch_bounds__(256) void transform_w_kernel(const int* __restrict__ w,
                                                          unsigned char* __restrict__ wt,
                                                          int K, int N) {
    __shared__ unsigned char tileT[64][72];
    int tx = threadIdx.x & 15;
    int ty = threadIdx.x >> 4;
    int n0 = blockIdx.x * 64;
    int k0 = blockIdx.y * 64;
#pragma unroll
    for (int r = 0; r < 4; ++r) {
        int row = ty * 4 + r;  // k_local
        int32x4 v = *(const int32x4*)&w[(size_t)(k0 + row) * N + n0 + tx * 4];
        tileT[tx * 4 + 0][row] = (unsigned char)(v.x & 255);
        tileT[tx * 4 + 1][row] = (unsigned char)(v.y & 255);
        tileT[tx * 4 + 2][row] = (unsigned char)(v.z & 255);
        tileT[tx * 4 + 3][row] = (unsigned char)(v.w & 255);
    }
    __syncthreads();
#pragma unroll
    for (int r = 0; r < 4; ++r) {
        int row = ty * 4 + r;  // n_local
        uchar4 v = *(const uchar4*)&tileT[row][tx * 4];
        *(uchar4*)&wt[(size_t)(n0 + row) * K + k0 + tx * 4] = v;
    }
}

// ---------------------------------------------------------------------------
// Kernel 3: int8 GEMM, 256x256 tile, 16x16x64 MFMA (r4's verified 0-conflict
// fragment family), 4-deep LDS circular buffer, register double-buffered
// fragments with per-tile-parity B sets, ONE barrier per K-tile, counted vmcnt.
// ---------------------------------------------------------------------------
__global__ __launch_bounds__(512, 2) void gemm_i8_1b(
    const char* __restrict__ A,   // [M][K] int8
    const char* __restrict__ Bt,  // [N][K] int8
    const int* __restrict__ bias,
    const int* __restrict__ shiftp,
    int* __restrict__ C,          // [M][N]
    int M, int N, int K) {
    __shared__ char smem[4 * TBUF];  // 128 KiB

    const int nbn = N / BN;
    const int nwg = gridDim.x;
    const int bid = blockIdx.x;
    const int cpx = nwg >> 3;  // nwg % 8 == 0 -> bijective XCD swizzle
    const int swz = (bid & 7) * cpx + (bid >> 3);
    const int m0 = (swz / nbn) * BM;
    const int n0 = (swz % nbn) * BN;

    const int t = threadIdx.x;
    const int lane = t & 63;
    const int wave = t >> 6;
    const int wr = wave >> 2;  // 0..1  (M half, 128 rows)
    const int wc = wave & 3;   // 0..3  (N quarter, 64 cols)

    // ---- staging geometry (pre-swizzled global source, linear LDS dest) ----
    const int s_row = t >> 2;
    const int s_col = ((t & 3) << 4) ^ (((t >> 3) & 3) << 4);
    const char* a_src = A + (size_t)(m0 + s_row) * K + s_col;
    const char* b_src = Bt + (size_t)(n0 + s_row) * K + s_col;
    const size_t jstr = (size_t)128 * K;
    char* lds_st = smem + t * 16;

    // ---- fragment-read geometry (r4 family: 16 rows x 4 col-groups) ----
    const int lr = lane & 15;
    const int lc = (lane >> 4) << 4;
    const int xr = ((lr >> 1) & 3) << 4;
    const int a_off = ((wr << 7) + lr) * 64 + (lc ^ xr);          // + mf*1024
    const int b_off = 16384 + ((wc << 6) + lr) * 64 + (lc ^ xr);  // + nf*1024

    int32x4 acc[8][4] = {};
    int32x4 afX[4], afY[4], bfX[4], bfY[4];

    const int nt = K / 64;  // 64 K-tiles (assumed even, >= 8)

#define GLL(src, dst)                                                 \
    __builtin_amdgcn_global_load_lds(                                 \
        (const __attribute__((address_space(1))) void*)(src),        \
        (__attribute__((address_space(3))) void*)(dst), 16, 0, 0)

#define FENCE asm volatile("" ::: "memory")
#define BARR                           \
    do {                               \
        FENCE;                         \
        __builtin_amdgcn_s_barrier();  \
        FENCE;                         \
    } while (0)
#define SB0 __builtin_amdgcn_sched_barrier(0)
#define LGKM0                                                   \
    do {                                                        \
        asm volatile("s_waitcnt lgkmcnt(0)" ::: "memory");      \
        SB0;                                                    \
    } while (0)
#define VMW(n)                                                  \
    do {                                                        \
        asm volatile("s_waitcnt vmcnt(" #n ")" ::: "memory");   \
        SB0;                                                    \
    } while (0)

    // One K-tile. Entry state: afX (mf0-3) and BFC (nf0-3) of tile TT loaded
    // and waited. One barrier. Every lgkmcnt(0) lands after a 16-MFMA burst.
    //   BFC = this tile's B regs, BFN = next tile's (parity-alternating names).
#define TILE(TT, BFC, BFN, DOSTAGE, DOREADN, WTAIL)                                    \
    do {                                                                               \
        const int base_ = ((TT) & 3) * TBUF;                                           \
        const int nbase_ = (((TT) + 1) & 3) * TBUF;                                    \
        const int sb_ = (((TT) + 3) & 3) * TBUF;                                       \
        const size_t kc_ = (size_t)((TT) + 3) * 64;                                    \
        BARR;                                                                          \
        _Pragma("unroll") for (int i = 0; i < 4; ++i)                                  \
            afY[i] = *(const int32x4*)&smem[base_ + a_off + (4 + i) * 1024];           \
        if (DOSTAGE) {                                                                 \
            GLL(a_src + kc_, lds_st + sb_);                                            \
            GLL(a_src + jstr + kc_, lds_st + sb_ + 8192);                              \
        }                                                                              \
        SB0;                                                                           \
        __builtin_amdgcn_s_setprio(1);                                                 \
        _Pragma("unroll") for (int mi = 0; mi < 4; ++mi)                               \
            _Pragma("unroll") for (int ni = 0; ni < 4; ++ni)                           \
                acc[mi][ni] = __builtin_amdgcn_mfma_i32_16x16x64_i8(                   \
                    afX[mi], BFC[ni], acc[mi][ni], 0, 0, 0);                           \
        __builtin_amdgcn_s_setprio(0);                                                 \
        LGKM0; /* afY landed under burst 1 */                                          \
        if (DOREADN) {                                                                 \
            _Pragma("unroll") for (int i = 0; i < 4; ++i)                              \
                afX[i] = *(const int32x4*)&smem[nbase_ + a_off + i * 1024];            \
            _Pragma("unroll") for (int i = 0; i < 4; ++i)                              \
                BFN[i] = *(const int32x4*)&smem[nbase_ + b_off + i * 1024];            \
        }                                                                              \
        if (DOSTAGE) {                                                                 \
            GLL(b_src + kc_, lds_st + sb_ + 16384);                                    \
            GLL(b_src + jstr + kc_, lds_st + sb_ + 24576);                             \
        }                                                                              \
        SB0;                                                                           \
        __builtin_amdgcn_s_setprio(1);                                                 \
        _Pragma("unroll") for (int mi = 0; mi < 4; ++mi)                               \
            _Pragma("unroll") for (int ni = 0; ni < 4; ++ni)                           \
                acc[4 + mi][ni] = __builtin_amdgcn_mfma_i32_16x16x64_i8(               \
                    afY[mi], BFC[ni], acc[4 + mi][ni], 0, 0, 0);                       \
        __builtin_amdgcn_s_setprio(0);                                                 \
        if (DOREADN) LGKM0; /* next-X landed under burst 2 */                          \
        WTAIL;                                                                         \
    } while (0)

    // ---- prologue: stage tiles 0,1,2 into bufs 0,1,2 ----
#pragma unroll
    for (int p = 0; p < 3; ++p) {
        GLL(a_src + p * 64, lds_st + p * TBUF);
        GLL(a_src + jstr + p * 64, lds_st + p * TBUF + 8192);
        GLL(b_src + p * 64, lds_st + p * TBUF + 16384);
        GLL(b_src + jstr + p * 64, lds_st + p * TBUF + 24576);
    }
    VMW(8);  // tile 0's 4 loads (oldest) done; tiles 1,2 in flight
    BARR;
    // preload X(0)
#pragma unroll
    for (int i = 0; i < 4; ++i) afX[i] = *(const int32x4*)&smem[a_off + i * 1024];
#pragma unroll
    for (int i = 0; i < 4; ++i) bfX[i] = *(const int32x4*)&smem[b_off + i * 1024];
    LGKM0;
    VMW(4);  // drain tile 1's loads (buffer t+1 is read inside tile 0)

    // ---- main loop ----
    // steady tail VMW(4): at end of tile t, newest 4 = stage(t+3);
    // drains stage(t+2), which tile t+1 reads (buffer t+2) after its BARR.
    int tt = 0;
    for (; tt < nt - 4; tt += 2) {
        TILE(tt, bfX, bfY, 1, 1, VMW(4));
        TILE(tt + 1, bfY, bfX, 1, 1, VMW(4));
    }
    // tt == nt-4 (even)
    TILE(nt - 4, bfX, bfY, 1, 1, VMW(4));   // stages tile nt-1; drains stage(nt-2)
    TILE(nt - 3, bfY, bfX, 0, 1, VMW(0));   // drains stage(nt-1) for reads in nt-2
    TILE(nt - 2, bfX, bfY, 0, 1, (void)0);  // reads buf nt-1 for next X
    TILE(nt - 1, bfY, bfX, 0, 0, (void)0);  // last tile

    // ---- epilogue: bias + shift, int32 store (16x16 C/D layout) ----
    const int s = *shiftp;
    const int crow = (lane >> 4) << 2;
    const int ccol = lane & 15;
    int bv[4];
#pragma unroll
    for (int nf = 0; nf < 4; ++nf) bv[nf] = bias[n0 + wc * 64 + nf * 16 + ccol];
#pragma unroll
    for (int mf = 0; mf < 8; ++mf) {
        const int grow0 = m0 + wr * 128 + mf * 16 + crow;
#pragma unroll
        for (int nf = 0; nf < 4; ++nf) {
            const int gcol = n0 + wc * 64 + nf * 16 + ccol;
#pragma unroll
            for (int r = 0; r < 4; ++r) {
                int y = acc[mf][nf][r] + bv[nf];
                y = (s > 0) ? (y >> s) : y;
                C[(size_t)(grow0 + r) * N + gcol] = y;
            }
        }
    }
#undef GLL
#undef FENCE
#undef BARR
#undef SB0
#undef LGKM0
#undef VMW
#undef TILE
}

// ---------------------------------------------------------------------------
extern "C" void kernel_launch(void* const* d_in, const int* in_sizes, int n_in,
                              void* d_out, int out_size, void* d_ws, size_t ws_size,
                              hipStream_t stream) {
    const int* x = (const int*)d_in[0];
    const int* w = (const int*)d_in[1];   // int8 values stored as int32
    const int* bias = (const int*)d_in[2];
    const int* shiftp = (const int*)d_in[3];
    int* out = (int*)d_out;

    const int N = in_sizes[2];      // 4096
    const int K = in_sizes[1] / N;  // 4096
    const int M = in_sizes[0] / K;  // 8192

    char* xp = (char*)d_ws;
    unsigned char* wt = (unsigned char*)d_ws + (size_t)M * K;

    int nvec = (int)(((long long)M * K) / 16);
    pack_x_kernel<<<(nvec + 255) / 256, 256, 0, stream>>>((const int32x4*)x, (int32x4*)xp, nvec);

    dim3 tgrid(N / 64, K / 64);
    transform_w_kernel<<<tgrid, 256, 0, stream>>>(w, wt, K, N);

    int nwg = (M / BM) * (N / BN);  // 512, %8==0
    gemm_i8_1b<<<nwg, 512, 0, stream>>>(xp, (const char*)wt, bias, shiftp, out, M, N, K);
}